// Round 5
// baseline (299.497 us; speedup 1.0000x reference)
//
#include <hip/hip_runtime.h>

// R5 — PROBE ROUND. dur_us = probe_same + probe_fill + relpos(known ~116us).
// probe_same: store-only, identical mapping to relpos (is the mapping the limit?)
// probe_fill: store-only, fillBuffer-like geometry (control, expect ~80us)
// relpos runs LAST and overwrites every output element -> correctness preserved.
//
// Decode: ~277us -> compute-chain gap; ~314us -> mapping gap; ~350us -> true
// 512MiB write roofline is 4.6 TB/s and R1 was optimal.

typedef float f4 __attribute__((ext_vector_type(4)));

constexpr int ROWS = 136;
constexpr int THREADS = 512;
constexpr int GRID = 1024;

// ---- probe A: exact relpos store mapping, no LDS/compute ----
__global__ __launch_bounds__(512)
void probe_same(f4* __restrict__ out)
{
    const int t = blockIdx.x * 512 + threadIdx.x;
    size_t o = (size_t)t;
    const f4 v = {1.0f, 1.0f, 1.0f, 1.0f};
    #pragma unroll 8
    for (int it = 0; it < 64; ++it) {
        out[o] = v;
        o += (size_t)524288;          // 8 MiB stride, 64 sweeps = 512 MiB
    }
}

// ---- probe B: fillBuffer-like geometry (256 blocks x 256 thr, grid-stride) ----
__global__ __launch_bounds__(256)
void probe_fill(f4* __restrict__ out)
{
    const int t = blockIdx.x * 256 + threadIdx.x;
    size_t o = (size_t)t;
    const f4 v = {2.0f, 2.0f, 2.0f, 2.0f};
    #pragma unroll 8
    for (int it = 0; it < 512; ++it) {
        out[o] = v;
        o += (size_t)65536;           // 1 MiB stride, 512 sweeps = 512 MiB
    }
}

// ---- the proven R1 kernel (115.9us), runs last, rewrites all of d_out ----
__global__ __launch_bounds__(THREADS)
void relpos_kernel(const int* __restrict__ asym,
                   const int* __restrict__ resid,
                   const int* __restrict__ ent,
                   const int* __restrict__ tok,
                   const int* __restrict__ sym,
                   const float* __restrict__ W,
                   f4* __restrict__ outv)
{
    __shared__ f4 sW[ROWS * 32];   // 69,632 B
    const int tid = threadIdx.x;

    const f4* Wv = reinterpret_cast<const f4*>(W);
    for (int k = tid; k < ROWS * 32; k += THREADS)
        sW[k] = Wv[k];
    __syncthreads();

    const int t  = blockIdx.x * THREADS + tid;
    const int c4 = t & 31;
    const int p0 = t >> 5;
    const int j  = p0 & 1023;
    int i        = p0 >> 10;

    const int aj = asym[j];
    const int rj = resid[j];
    const int ej = ent[j];
    const int tj = tok[j];
    const int sj = sym[j];

    const f4 vE = sW[130 * 32 + c4];

    size_t oidx = (size_t)t;
    #pragma unroll 4
    for (int it = 0; it < 64; ++it) {
        const int ai = asym[i];
        const int ri = resid[i];
        const int ei = ent[i];
        const int ti = tok[i];
        const int si = sym[i];

        const bool sc = (ai == aj);
        const bool sr = (ri == rj);

        int dres = min(max(rj - ri + 32, 0), 64);
        int dtok = min(max(tj - ti + 32, 0), 64);
        int dch  = min(max(sj - si + 2, 0), 4);
        if (sc)        { dres = 64; dch = 4; }
        if (sc || sr)  { dtok = 64; }
        const float se = (ei == ej) ? 1.0f : 0.0f;

        const f4 v0 = sW[dres * 32 + c4];
        const f4 v1 = sW[(65 + dtok) * 32 + c4];
        const f4 v3 = sW[(131 + dch) * 32 + c4];

        f4 r;
        r.x = fmaf(se, vE.x, v0.x + v1.x) + v3.x;
        r.y = fmaf(se, vE.y, v0.y + v1.y) + v3.y;
        r.z = fmaf(se, vE.z, v0.z + v1.z) + v3.z;
        r.w = fmaf(se, vE.w, v0.w + v1.w) + v3.w;

        outv[oidx] = r;
        oidx += (size_t)GRID * THREADS;
        i += 16;
    }
}

extern "C" void kernel_launch(void* const* d_in, const int* in_sizes, int n_in,
                              void* d_out, int out_size, void* d_ws, size_t ws_size,
                              hipStream_t stream) {
    const int*   asym  = (const int*)  d_in[0];
    const int*   resid = (const int*)  d_in[1];
    const int*   ent   = (const int*)  d_in[2];
    const int*   tok   = (const int*)  d_in[3];
    const int*   sym   = (const int*)  d_in[4];
    const float* W     = (const float*)d_in[5];
    f4* outv = (f4*)d_out;

    // probes first (scribble on d_out), real kernel last (rewrites everything)
    probe_same<<<1024, 512, 0, stream>>>(outv);
    probe_fill<<<256, 256, 0, stream>>>(outv);
    relpos_kernel<<<GRID, THREADS, 0, stream>>>(asym, resid, ent, tok, sym, W, outv);
}

// Round 6
// 127.828 us; speedup vs baseline: 2.3430x; 2.3430x over previous
//
#include <hip/hip_runtime.h>

// RelativePositionEncoding: out[i,j,c] = W[dres][c] + W[65+dtok][c]
//                                      + same_entity*W[130][c] + W[131+dch][c]
// B=1, N=1024, CZ=128. Output 512 MiB fp32 — HBM-write-bound.
//
// R6: fill-mimicking geometry. R5 probe decode: probe_same+probe_fill=183.5us,
// so our-mapping store-only <= 103.5us while fill geometry can be 80us.
// This version mirrors fillBuffer's shape: 256-thread blocks, 512 blocks
// (2/CU, 8 waves/CU), 256 iterations/thread, each iteration-sweep writes a
// contiguous 2 MiB slab. i is block-uniform -> SALU unpack; 8 back-to-back
// stores per batch. If this lands ~116us the 512MiB write roofline is
// ~5.8 TB/s and R1 was already optimal.

typedef float f4 __attribute__((ext_vector_type(4)));

constexpr int ROWS = 136;          // 65 rel_pos | 65 rel_token | 1 entity | 5 rel_chain
constexpr int THREADS = 256;
constexpr int GRID = 512;          // 131,072 threads; each stores 256 f4
constexpr int ITERS = 256;
constexpr int BATCH = 8;

__global__ __launch_bounds__(THREADS, 2)
void relpos_kernel(const int* __restrict__ asym,
                   const int* __restrict__ resid,
                   const int* __restrict__ ent,
                   const int* __restrict__ tok,
                   const int* __restrict__ sym,
                   const float* __restrict__ W,
                   f4* __restrict__ outv)
{
    __shared__ f4 sW[ROWS * 32];     // 69,632 B
    __shared__ uint32_t sPk[1024];   // 4 KB packed scalars (73.7 KB -> 2 blocks/CU)
    const int tid = threadIdx.x;

    // ---- stage W (coalesced f4) + pack the 5 int arrays ----
    const f4* Wv = reinterpret_cast<const f4*>(W);
    for (int k = tid; k < ROWS * 32; k += THREADS)
        sW[k] = Wv[k];
    for (int k = tid; k < 1024; k += THREADS) {
        // asym 3b | resid 10b | ent 2b | tok 10b | sym 2b
        sPk[k] = (uint32_t)asym[k]
               | ((uint32_t)resid[k] << 3)
               | ((uint32_t)ent[k]   << 13)
               | ((uint32_t)tok[k]   << 15)
               | ((uint32_t)sym[k]   << 25);
    }
    __syncthreads();

    // ---- mapping: f4 index o = t + it*131072 ----
    // c4 = t&31 fixed; j = (t>>5)&1023 fixed; i = (bid>>7) + 4*it (block-uniform).
    const int t  = blockIdx.x * THREADS + tid;
    const int c4 = t & 31;
    const int j  = (t >> 5) & 1023;
    const int i0 = blockIdx.x >> 7;          // in [0,4), block-uniform

    const uint32_t pkj = sPk[j];
    const int aj  = pkj & 7;
    const int rjb = ((pkj >> 3)  & 1023) + 32;
    const int ej  = (pkj >> 13) & 3;
    const int tjb = ((pkj >> 15) & 1023) + 32;
    const int sjb = ((pkj >> 25) & 3) + 2;
    const int rj  = rjb - 32;

    const f4 vE = sW[130 * 32 + c4];         // entity row hoisted

    size_t o = (size_t)t;
    for (int b = 0; b < ITERS / BATCH; ++b) {
        f4 r[BATCH];
        #pragma unroll
        for (int u = 0; u < BATCH; ++u) {
            const int i = i0 + 4 * (b * BATCH + u);
            // block-uniform i -> broadcast LDS read + readfirstlane -> SALU
            const uint32_t pkc =
                (uint32_t)__builtin_amdgcn_readfirstlane((int)sPk[i]);

            const int ai = pkc & 7;
            const int ri = (pkc >> 3)  & 1023;
            const int ei = (pkc >> 13) & 3;
            const int ti = (pkc >> 15) & 1023;
            const int si = (pkc >> 25) & 3;

            const bool sc  = (ai == aj);
            const bool scr = sc || (ri == rj);

            int dres = min(max(rjb - ri, 0), 64);
            int dtok = min(max(tjb - ti, 0), 64);
            int dch  = min(max(sjb - si, 0), 4);
            if (sc)  { dres = 64; dch = 4; }
            if (scr) { dtok = 64; }
            const float se = (ei == ej) ? 1.0f : 0.0f;

            const f4 v0 = sW[dres * 32 + c4];
            const f4 v1 = sW[(65 + dtok) * 32 + c4];
            const f4 v3 = sW[(131 + dch) * 32 + c4];

            // reference fp32 order: ((t0 + t1) + se*w130) + t3
            r[u].x = fmaf(se, vE.x, v0.x + v1.x) + v3.x;
            r[u].y = fmaf(se, vE.y, v0.y + v1.y) + v3.y;
            r[u].z = fmaf(se, vE.z, v0.z + v1.z) + v3.z;
            r[u].w = fmaf(se, vE.w, v0.w + v1.w) + v3.w;
        }
        // 8 back-to-back 16B stores; each iteration-sweep = contiguous 2 MiB slab
        #pragma unroll
        for (int u = 0; u < BATCH; ++u) {
            outv[o] = r[u];
            o += (size_t)131072;      // i += 4
        }
    }
}

extern "C" void kernel_launch(void* const* d_in, const int* in_sizes, int n_in,
                              void* d_out, int out_size, void* d_ws, size_t ws_size,
                              hipStream_t stream) {
    const int*   asym  = (const int*)  d_in[0];
    const int*   resid = (const int*)  d_in[1];
    const int*   ent   = (const int*)  d_in[2];
    const int*   tok   = (const int*)  d_in[3];
    const int*   sym   = (const int*)  d_in[4];
    const float* W     = (const float*)d_in[5];
    f4* outv = (f4*)d_out;

    relpos_kernel<<<GRID, THREADS, 0, stream>>>(asym, resid, ent, tok, sym, W, outv);
}